// Round 16
// baseline (185.031 us; speedup 1.0000x reference)
//
#include <hip/hip_runtime.h>
#include <hip/hip_bf16.h>

// ---------------------------------------------------------------------------
// DropBlock fused dual-conv as implicit GEMM, 32x32x16 MFMA shape.
// Tile 256x128, 256 threads (4 waves of 128x64 = 4m x 2n frags of 32x32),
// TWO blocks co-resident per CU (LDS padded to 57344 to pin exactly 2).
//   M = 50176 = 196*256 exactly, N = 512 (4 quarters of 128), K = 2304.
//   72 K-tiles of 32 (2 k-steps of 16); 2-slot LDS double-buffer
//   (24576 B/slot: A 16K + B 8K), depth-1, VM(0)+BAR per tile.
// Per tile: STG(t+1) [6 uniform gll16] -> ds 12 reads (ks0:6, ks1:6) ->
//   LGKM(6) -> 8x mfma_32x32x16 (ks0) -> LGKM(0) -> 8x mfma (ks1) -> VM0 -> BAR.
// A/B frag read (lane l): row = base + (l&31); k-slot sl = ks*2 + (l>>5);
//   phys p = sl ^ (((l&31)>>1)&3)  [matches store-side swizzle; <=2-way banks]
// C/D 32x32 layout: col(channel) = lane&31, row(pos) = (r&3)+8*(r>>2)+4*(l>>5).
// ws: [0,4) dropped | [1024,+50176) sel | [65536,+29491200) xt bf16
//     [64][30][30][256] | [+2359296) wt bf16 [72 t][4 nq][128 rows][4 ps][8]
// ---------------------------------------------------------------------------

typedef __bf16  bf16x8 __attribute__((ext_vector_type(8)));
typedef float   f32x16 __attribute__((ext_vector_type(16)));
typedef short   short8 __attribute__((ext_vector_type(8)));
typedef unsigned int u32;
typedef unsigned short u16;

#define XT_OFF     65536
#define WT_OFF     (65536 + 29491200)
#define SEL_OFF    1024
#define SLOT       24576

__device__ __forceinline__ u16 f2bf(float v) {
    u32 u = __float_as_uint(v);
    u32 r = (u + 0x7FFFu + ((u >> 16) & 1u)) >> 16;
    return (u16)r;
}

__device__ __forceinline__ void gll16(const void* g, void* l) {
    __builtin_amdgcn_global_load_lds(
        (const __attribute__((address_space(1))) u32*)g,
        (__attribute__((address_space(3))) u32*)l, 16, 0, 0);
}

// ---------------- fused prep: xt transform + wt swizzle + mask -------------
__global__ void prep_kernel(const float* __restrict__ x,
                            const float* __restrict__ wl,
                            const float* __restrict__ wp,
                            const float* __restrict__ mu,
                            u16* __restrict__ xt, u16* __restrict__ wt,
                            unsigned char* __restrict__ sel,
                            int* __restrict__ dropped) {
    int b = blockIdx.x, tid = threadIdx.x;
    if (b < 1920) {                                   // ---- xt: 64*30 rows
        int n = b / 30, oh = b % 30;
        u16* row = xt + (size_t)(n * 30 + oh) * 30 * 256;
        if (oh == 0 || oh == 29) {                    // halo rows: full zero
            u32* r32 = (u32*)row;
            #pragma unroll
            for (int i = 0; i < 15; ++i) r32[i * 256 + tid] = 0;
            return;
        }
        int h = oh - 1;
        row[tid] = 0;
        row[29 * 256 + tid] = 0;
        const float* src = x + ((size_t)(n * 256 + tid) * 28 + h) * 28;
        float f[28];
        #pragma unroll
        for (int q = 0; q < 7; ++q) {
            float4 v = *(const float4*)(src + q * 4);
            f[q * 4 + 0] = v.x; f[q * 4 + 1] = v.y;
            f[q * 4 + 2] = v.z; f[q * 4 + 3] = v.w;
        }
        #pragma unroll
        for (int w = 0; w < 28; ++w)
            row[(1 + w) * 256 + tid] = f2bf(f[w]);
    } else if (b < 2496) {                            // ---- wt blocks (x8 vec)
        // elem layout: block bb = t*4 + nq: [row 0..127][ps 0..3][jj 0..7]
        // phys slot ps holds logical channels (ps ^ ((row>>1)&3))*8 + jj
        int gid = (b - 1920) * 256 + tid;             // 147456 exact
        int base = gid << 3;                          // 8 elems, jj = 0..7
        int bb = base >> 12;                          // 0..287
        int e = base & 4095;
        int t = bb >> 2, nq = bb & 3;
        int kk = t >> 3;                              // tap 0..8
        int row = e >> 5, ps = (e & 31) >> 3;
        int c0 = (t & 7) * 32 + ((ps ^ ((row >> 1) & 3)) << 3);
        int o = nq * 128 + row;
        const float* wsrc = (o < 256) ? wl : wp;
        const float* wr = wsrc + ((size_t)(o & 255) * 256 + c0) * 9 + kk;
        short8 v;
        #pragma unroll
        for (int j = 0; j < 8; ++j) v[j] = (short)f2bf(wr[j * 9]);
        *(short8*)(wt + base) = v;
    } else {                                          // ---- mask + pooled sel
        int m = (b - 2496) * 256 + tid;               // 196*256 exact
        int n = m / 784, rem = m % 784;
        int h = rem / 28, w = rem % 28;
        const float g = (float)(0.1 / 49.0);
        const float* un = mu + n * 784;
        int p = 0;
        for (int dy = -3; dy <= 3; ++dy) {
            int hh = h + dy;
            if (hh < 0 || hh >= 28) continue;
            for (int dx = -3; dx <= 3; ++dx) {
                int ww = w + dx;
                if (ww < 0 || ww >= 28) continue;
                p |= (un[hh * 28 + ww] < g) ? 1 : 0;
            }
        }
        sel[m] = (unsigned char)p;
        unsigned long long bl = __ballot(p);
        if ((tid & 63) == 0) atomicAdd(dropped, __popcll(bl));
    }
}

// ---------------- implicit-GEMM conv + select + scale ----------------------
__global__ __launch_bounds__(256, 2)
void conv_kernel(const char* __restrict__ xt,    // bf16 padded NHWC (bytes)
                 const char* __restrict__ wt,    // bf16 swizzled blocks (bytes)
                 const unsigned char* __restrict__ sel,
                 const int* __restrict__ dropped,
                 float* __restrict__ out) {
    __shared__ char smem[57344];                  // 2 slots x 24576 + pad
    const int tid = threadIdx.x;
    const int lb = (blockIdx.x & 7) * 98 + (blockIdx.x >> 3);  // 784 = 8*98
    const int bm = lb >> 2;                  // 196 M-tiles of 256 positions
    const int bnq = lb & 3;                  // N-quarter: 0,1 -> a ; 2,3 -> b
    const int lane = tid & 63, wave = tid >> 6;
    const int lane31 = lane & 31, hl = lane >> 5;
    const int wm = wave >> 1, wn = wave & 1; // per-wave 128 x 64 output

    // --- A staging source bases; source-side swizzle folded in ---
    // op i: rows i*64 + (tid>>2), phys slot = tid&3
    long pbA[4];
    {
        int swz = ((tid & 3) ^ ((tid >> 3) & 3)) << 4;
        #pragma unroll
        for (int i = 0; i < 4; ++i) {
            int r = i * 64 + (tid >> 2);
            int m = bm * 256 + r;                     // max 50175: exact fit
            int n = m / 784, rem = m % 784;
            pbA[i] = (long)(((n * 30 + rem / 28 + 1) * 30 + (rem % 28 + 1)) * 512
                            + swz);
        }
    }

    f32x16 acc[4][2];
    #pragma unroll
    for (int i = 0; i < 4; ++i)
        #pragma unroll
        for (int j = 0; j < 2; ++j)
            acc[i][j] = (f32x16){};

    const int q   = (lane31 >> 1) & 3;                   // read-swizzle key
    const int so0 = (hl ^ q) << 4;                       // ks0 slot offset
    const int so1 = ((2 + hl) ^ q) << 4;                 // ks1 slot offset
    const int arb = (wm * 128 + lane31) << 6;            // A row base in slot
    const int brb = 16384 + ((wn * 64 + lane31) << 6);   // B row base in slot

#define AON(TC) ((long)((TC) >> 3) / 3 * 15360 + (long)(((TC) >> 3) % 3) * 512 \
                 - 15872 + (long)(((TC) & 7) << 6))
#define STG(TC, SL) { char* sd_ = smem + (SL) * SLOT;                       \
        const long ao_ = AON(TC);                                           \
        gll16(xt + pbA[0] + ao_, sd_ + (tid << 4));                         \
        gll16(xt + pbA[1] + ao_, sd_ + 4096 + (tid << 4));                  \
        gll16(xt + pbA[2] + ao_, sd_ + 8192 + (tid << 4));                  \
        gll16(xt + pbA[3] + ao_, sd_ + 12288 + (tid << 4));                 \
        const char* wb_ = wt + ((size_t)((TC) * 4 + bnq) << 13);            \
        gll16(wb_ + (tid << 4), sd_ + 16384 + (tid << 4));                  \
        gll16(wb_ + 4096 + (tid << 4), sd_ + 20480 + (tid << 4)); }
#define DS_A(dst, SL, SO) { const char* sb_ = smem + (SL) * SLOT;           \
        _Pragma("unroll")                                                   \
        for (int fm = 0; fm < 4; ++fm)                                      \
            dst[fm] = *(const bf16x8*)(sb_ + arb + fm * 2048 + (SO)); }
#define DS_B(dst, SL, SO) { const char* sb_ = smem + (SL) * SLOT;           \
        _Pragma("unroll")                                                   \
        for (int nf = 0; nf < 2; ++nf)                                      \
            dst[nf] = *(const bf16x8*)(sb_ + brb + nf * 2048 + (SO)); }
#define MM(AV, BV) { __builtin_amdgcn_s_setprio(1);                         \
        _Pragma("unroll")                                                   \
        for (int fm = 0; fm < 4; ++fm)                                      \
            _Pragma("unroll")                                               \
            for (int nf = 0; nf < 2; ++nf)                                  \
                acc[fm][nf] = __builtin_amdgcn_mfma_f32_32x32x16_bf16(      \
                    AV[fm], BV[nf], acc[fm][nf], 0, 0, 0);                  \
        __builtin_amdgcn_s_setprio(0); }
#define LGKM(N) { asm volatile("s_waitcnt lgkmcnt(" #N ")" ::: "memory");   \
                  __builtin_amdgcn_sched_barrier(0); }
#define VM0     { asm volatile("s_waitcnt vmcnt(0)" ::: "memory");          \
                  __builtin_amdgcn_sched_barrier(0); }
#define BAR     asm volatile("s_barrier" ::: "memory")

    bf16x8 av0[4], av1[4], bv0[2], bv1[2];

    // --- prologue: stage tile 0 into slot 0 ---
    STG(0, 0);
    VM0;
    BAR;

    for (int t = 0; t < 72; ++t) {
        const int sc = t & 1, ss = sc ^ 1;
        if (t < 71) STG(t + 1, ss);
        DS_A(av0, sc, so0);
        DS_B(bv0, sc, so0);
        DS_A(av1, sc, so1);
        DS_B(bv1, sc, so1);
        LGKM(6);                    // ks0 frags ready; ks1 still landing
        MM(av0, bv0);
        LGKM(0);                    // ks1 ready
        MM(av1, bv1);
        VM0;                        // tile t+1 staged & landed
        BAR;
    }

    // --- epilogue: per-wave LDS transpose -> coalesced predicated stores ---
    float scale = 50176.0f / (float)(50176 - *dropped);
    float* ep = (float*)smem + wave * 2080;      // private [32 ch][65] f32
    __syncthreads();
    #pragma unroll
    for (int rp = 0; rp < 2; ++rp)               // m-frag pair (64 positions)
        #pragma unroll
        for (int nf = 0; nf < 2; ++nf) {         // n-frag (32 channels)
            #pragma unroll
            for (int fp = 0; fp < 2; ++fp) {
                const int fm = rp * 2 + fp;
                #pragma unroll
                for (int r = 0; r < 16; ++r)
                    ep[lane31 * 65 + fp * 32 + (r & 3) + 8 * (r >> 2) + 4 * hl]
                        = acc[fm][nf][r];
            }
            __syncthreads();
            {
                int p = bm * 256 + wm * 128 + rp * 64 + lane;
                int n = p / 784, rem = p % 784;
                unsigned char sv = sel[p];
                bool want = (bnq >= 2) ? (sv != 0) : (sv == 0);
                size_t ob = (size_t)n * 200704 + rem;
                if (want) {
                    #pragma unroll
                    for (int ch = 0; ch < 32; ++ch) {
                        int c = (bnq * 128 + wn * 64 + nf * 32 + ch) & 255;
                        out[ob + (size_t)c * 784] = ep[ch * 65 + lane] * scale;
                    }
                }
            }
            __syncthreads();
        }
#undef AON
#undef STG
#undef DS_A
#undef DS_B
#undef MM
#undef LGKM
#undef VM0
#undef BAR
}

// ---------------------------------------------------------------------------
extern "C" void kernel_launch(void* const* d_in, const int* in_sizes, int n_in,
                              void* d_out, int out_size, void* d_ws, size_t ws_size,
                              hipStream_t stream) {
    const float* x  = (const float*)d_in[0];
    const float* wl = (const float*)d_in[1];
    const float* wp = (const float*)d_in[2];
    const float* mu = (const float*)d_in[3];
    float* out = (float*)d_out;
    char* ws = (char*)d_ws;

    int* dropped = (int*)ws;
    unsigned char* sel = (unsigned char*)(ws + SEL_OFF);
    u16* xt = (u16*)(ws + XT_OFF);
    u16* wt = (u16*)(ws + WT_OFF);

    hipMemsetAsync(ws, 0, 4, stream);

    prep_kernel<<<2692, 256, 0, stream>>>(x, wl, wp, mu, xt, wt, sel, dropped);
    conv_kernel<<<784, 256, 0, stream>>>((const char*)xt, (const char*)wt,
                                         sel, dropped, out);
}

// Round 17
// 115.962 us; speedup vs baseline: 1.5956x; 1.5956x over previous
//
#include <hip/hip_runtime.h>
#include <hip/hip_bf16.h>

// ---------------------------------------------------------------------------
// DropBlock fused dual-conv, LIST-COMPACTED implicit GEMM (each position
// computes ONLY its selected branch -> half the FLOPs of dual-conv).
//   prep: mask -> per-position sel; ballot-compact positions into
//         listA (sel=0 -> w_layer3) / listB (sel=1 -> w_pre).
//   conv: tile = 224 list-positions x 128 channels of ONE branch.
//         Virtual tiles: [0,naT) -> listA, [naT,naT+nbT) -> listB; grid 456
//         (8x57 XCD-bijective), empty tiles exit. Ragged tails clamp to
//         cnt-1 (duplicate rows -> duplicate identical stores, benign).
// Conv core = round-12 proven pipeline: 256 thr (4 waves of 112x64),
//   2-slot LDS dbuf (22528 B/slot, padded 55296 -> exactly 2 blocks/CU),
//   depth-1 VM(0)+BAR per K-tile, split LGKM, setprio, 16x16x32 MFMA.
// ws: [0,4) cntB(dropped) | [4,8) cntA | [65536,+29491200) xt bf16
//     [64][30][30][256] | [29556736,+2359296) wt bf16 [72][4 nq][128][4 ps][8]
//     | [31916032,+200704) listA | [32116736,+200704) listB
// ---------------------------------------------------------------------------

typedef __bf16  bf16x8 __attribute__((ext_vector_type(8)));
typedef float   f32x4  __attribute__((ext_vector_type(4)));
typedef short   short8 __attribute__((ext_vector_type(8)));
typedef unsigned int u32;
typedef unsigned short u16;

#define XT_OFF     65536
#define WT_OFF     29556736
#define LISTA_OFF  31916032
#define LISTB_OFF  32116736
#define SLOT       22528

__device__ __forceinline__ u16 f2bf(float v) {
    u32 u = __float_as_uint(v);
    u32 r = (u + 0x7FFFu + ((u >> 16) & 1u)) >> 16;
    return (u16)r;
}

__device__ __forceinline__ void gll16(const void* g, void* l) {
    __builtin_amdgcn_global_load_lds(
        (const __attribute__((address_space(1))) u32*)g,
        (__attribute__((address_space(3))) u32*)l, 16, 0, 0);
}

// ---------------- fused prep: xt transform + wt swizzle + mask/lists -------
__global__ void prep_kernel(const float* __restrict__ x,
                            const float* __restrict__ wl,
                            const float* __restrict__ wp,
                            const float* __restrict__ mu,
                            u16* __restrict__ xt, u16* __restrict__ wt,
                            int* __restrict__ listA, int* __restrict__ listB,
                            int* __restrict__ cntB, int* __restrict__ cntA) {
    int b = blockIdx.x, tid = threadIdx.x;
    if (b < 1920) {                                   // ---- xt: 64*30 rows
        int n = b / 30, oh = b % 30;
        u16* row = xt + (size_t)(n * 30 + oh) * 30 * 256;
        if (oh == 0 || oh == 29) {                    // halo rows: full zero
            u32* r32 = (u32*)row;
            #pragma unroll
            for (int i = 0; i < 15; ++i) r32[i * 256 + tid] = 0;
            return;
        }
        int h = oh - 1;
        row[tid] = 0;
        row[29 * 256 + tid] = 0;
        const float* src = x + ((size_t)(n * 256 + tid) * 28 + h) * 28;
        float f[28];
        #pragma unroll
        for (int q = 0; q < 7; ++q) {
            float4 v = *(const float4*)(src + q * 4);
            f[q * 4 + 0] = v.x; f[q * 4 + 1] = v.y;
            f[q * 4 + 2] = v.z; f[q * 4 + 3] = v.w;
        }
        #pragma unroll
        for (int w = 0; w < 28; ++w)
            row[(1 + w) * 256 + tid] = f2bf(f[w]);
    } else if (b < 2496) {                            // ---- wt blocks (x8 vec)
        // block bb = t*4 + nq: [row 0..127][ps 0..3][jj 0..7]
        // phys slot ps holds logical channels (ps ^ ((row>>1)&3))*8 + jj
        int gid = (b - 1920) * 256 + tid;             // 147456 exact
        int base = gid << 3;                          // 8 elems, jj = 0..7
        int bb = base >> 12;                          // 0..287
        int e = base & 4095;
        int t = bb >> 2, nq = bb & 3;
        int kk = t >> 3;                              // tap 0..8
        int row = e >> 5, ps = (e & 31) >> 3;
        int c0 = (t & 7) * 32 + ((ps ^ ((row >> 1) & 3)) << 3);
        int o = nq * 128 + row;
        const float* wsrc = (o < 256) ? wl : wp;
        const float* wr = wsrc + ((size_t)(o & 255) * 256 + c0) * 9 + kk;
        short8 v;
        #pragma unroll
        for (int j = 0; j < 8; ++j) v[j] = (short)f2bf(wr[j * 9]);
        *(short8*)(wt + base) = v;
    } else {                                          // ---- mask + list build
        __shared__ int wbase[8];
        int m = (b - 2496) * 256 + tid;               // 196*256 exact
        int n = m / 784, rem = m % 784;
        int h = rem / 28, w = rem % 28;
        const float g = (float)(0.1 / 49.0);
        const float* un = mu + n * 784;
        int p = 0;
        for (int dy = -3; dy <= 3; ++dy) {
            int hh = h + dy;
            if (hh < 0 || hh >= 28) continue;
            for (int dx = -3; dx <= 3; ++dx) {
                int ww = w + dx;
                if (ww < 0 || ww >= 28) continue;
                p |= (un[hh * 28 + ww] < g) ? 1 : 0;
            }
        }
        unsigned long long ball = __ballot(p);
        int wid = tid >> 6, ln = tid & 63;
        int c1 = __popcll(ball);
        if (ln == 0) {
            wbase[wid]     = atomicAdd(cntB, c1);
            wbase[4 + wid] = atomicAdd(cntA, 64 - c1);
        }
        __syncthreads();
        int rank1 = __popcll(ball & ((1ULL << ln) - 1));
        int rank0 = ln - rank1;
        if (p) listB[wbase[wid] + rank1] = m;
        else   listA[wbase[4 + wid] + rank0] = m;
    }
}

// ---------------- list-compacted implicit-GEMM conv + scale ----------------
__global__ __launch_bounds__(256, 2)
void conv_kernel(const char* __restrict__ xt,    // bf16 padded NHWC (bytes)
                 const char* __restrict__ wt,    // bf16 swizzled blocks (bytes)
                 const int* __restrict__ listA,
                 const int* __restrict__ listB,
                 const int* __restrict__ dropped,   // = cntB
                 float* __restrict__ out) {
    __shared__ char smem[55296];                  // 2 slots x 22528 (+pad)
    const int tid = threadIdx.x;
    const int lb = (blockIdx.x & 7) * 57 + (blockIdx.x >> 3);  // 456 = 8*57
    const int vt = lb >> 1;                  // virtual tile 0..227
    const int nh = lb & 1;                   // channel half of the branch
    const int cB = *dropped;
    const int cA = 50176 - cB;
    const int naT = (cA + 223) / 224;
    const int nbT = (cB + 223) / 224;
    if (vt >= naT + nbT) return;             // block-uniform exit
    const int branch = (vt >= naT) ? 1 : 0;
    const int tix = branch ? (vt - naT) : vt;
    const int cnt = branch ? cB : cA;
    const int* lst = branch ? listB : listA;
    const int nq = branch * 2 + nh;          // wt quarter
    const int lane = tid & 63, wave = tid >> 6;
    const int lane15 = lane & 15, grp = lane >> 4;
    const int wm = wave >> 1, wn = wave & 1; // per-wave 112 x 64 output

    // --- A staging source bases (via list gather); swizzle folded in ---
    // op i (i<3): rows i*64 + (tid>>2); op 3 (tid<128): rows 192 + (tid>>2)
    long pbA[4];
    {
        int swz = ((tid & 3) ^ ((tid >> 3) & 3)) << 4;
        #pragma unroll
        for (int i = 0; i < 4; ++i) {
            int r = i * 64 + (tid >> 2);
            int idx = tix * 224 + r;
            if (idx >= cnt) idx = cnt - 1;   // ragged-tail clamp (dup rows)
            int m = lst[idx];
            int n = m / 784, rem = m % 784;
            pbA[i] = (long)(((n * 30 + rem / 28 + 1) * 30 + (rem % 28 + 1)) * 512
                            + swz);
        }
    }

    f32x4 acc[7][4];
    #pragma unroll
    for (int i = 0; i < 7; ++i)
        #pragma unroll
        for (int j = 0; j < 4; ++j)
            acc[i][j] = (f32x4){0.f, 0.f, 0.f, 0.f};

    const int so  = (grp ^ ((lane15 >> 1) & 3)) << 4;        // read swizzle
    const int arb = wm * 7168 + (lane15 << 6) + so;          // A base in slot
    const int brb = 14336 + wn * 4096 + (lane15 << 6) + so;  // B base in slot

#define AON(TC) ((long)((TC) >> 3) / 3 * 15360 + (long)(((TC) >> 3) % 3) * 512 \
                 - 15872 + (long)(((TC) & 7) << 6))
#define STG(TC, SL) { char* sd_ = smem + (SL) * SLOT;                       \
        const long ao_ = AON(TC);                                           \
        gll16(xt + pbA[0] + ao_, sd_ + (tid << 4));                         \
        gll16(xt + pbA[1] + ao_, sd_ + 4096 + (tid << 4));                  \
        gll16(xt + pbA[2] + ao_, sd_ + 8192 + (tid << 4));                  \
        if (tid < 128) gll16(xt + pbA[3] + ao_, sd_ + 12288 + (tid << 4));  \
        const char* wb_ = wt + ((size_t)((TC) * 4 + nq) << 13);             \
        gll16(wb_ + (tid << 4), sd_ + 14336 + (tid << 4));                  \
        gll16(wb_ + 4096 + (tid << 4), sd_ + 18432 + (tid << 4)); }
#define DS_AV0(dst, SL) { const char* sb_ = smem + (SL) * SLOT;             \
        _Pragma("unroll")                                                   \
        for (int fm = 0; fm < 4; ++fm)                                      \
            dst[fm] = *(const bf16x8*)(sb_ + arb + (fm << 10)); }
#define DS_AV1(dst, SL) { const char* sb_ = smem + (SL) * SLOT + 4096;      \
        _Pragma("unroll")                                                   \
        for (int fm = 0; fm < 3; ++fm)                                      \
            dst[fm] = *(const bf16x8*)(sb_ + arb + (fm << 10)); }
#define DS_BV(dst, SL) { const char* sb_ = smem + (SL) * SLOT;              \
        _Pragma("unroll")                                                   \
        for (int fn = 0; fn < 4; ++fn)                                      \
            dst[fn] = *(const bf16x8*)(sb_ + brb + (fn << 10)); }
#define MM(A0_, NF, AV, BV) { __builtin_amdgcn_s_setprio(1);                \
        _Pragma("unroll")                                                   \
        for (int fm = 0; fm < (NF); ++fm)                                   \
            _Pragma("unroll")                                               \
            for (int fn = 0; fn < 4; ++fn)                                  \
                acc[(A0_)+fm][fn] = __builtin_amdgcn_mfma_f32_16x16x32_bf16( \
                    AV[fm], BV[fn], acc[(A0_)+fm][fn], 0, 0, 0);            \
        __builtin_amdgcn_s_setprio(0); }
#define LGKM(N) { asm volatile("s_waitcnt lgkmcnt(" #N ")" ::: "memory");   \
                  __builtin_amdgcn_sched_barrier(0); }
#define VM0     { asm volatile("s_waitcnt vmcnt(0)" ::: "memory");          \
                  __builtin_amdgcn_sched_barrier(0); }
#define BAR     asm volatile("s_barrier" ::: "memory")

    bf16x8 av0[4], av1[3], bv[4];

    // --- prologue: stage tile 0 into slot 0 ---
    STG(0, 0);
    VM0;
    BAR;

    for (int t = 0; t < 72; ++t) {
        const int sc = t & 1, ss = sc ^ 1;
        if (t < 71) STG(t + 1, ss);
        DS_AV0(av0, sc);
        DS_BV(bv, sc);
        DS_AV1(av1, sc);
        LGKM(3);                    // av0+bv ready; av1 still landing
        MM(0, 4, av0, bv);
        LGKM(0);                    // av1 ready
        MM(4, 3, av1, bv);
        VM0;                        // tile t+1 staged & landed
        BAR;
    }

    // --- epilogue: per-wave LDS transpose -> coalesced scaled stores ---
    float scale = 50176.0f / (float)(50176 - cB);
    float* ep = (float*)smem + wave * 2080;      // private [32][65] f32
    __syncthreads();
    #pragma unroll
    for (int rr = 0; rr < 4; ++rr) {
        const int r2 = rr & 1;        // 32-channel half of this wave's 64
        const int mh = rr >> 1;       // m half: 0 -> 64 pos, 1 -> 48 pos
        const int nf = mh ? 3 : 4;
        for (int fm2 = 0; fm2 < nf; ++fm2)
            #pragma unroll
            for (int f2 = 0; f2 < 2; ++f2)
                #pragma unroll
                for (int j = 0; j < 4; ++j)
                    ep[(f2 * 16 + lane15) * 65 + fm2 * 16 + grp * 4 + j] =
                        acc[mh * 4 + fm2][r2 * 2 + f2][j];
        __syncthreads();
        {
            int gidx = tix * 224 + wm * 112 + mh * 64 + lane;
            if ((mh == 0 || lane < 48) && gidx < cnt) {
                int m = lst[gidx];
                int n = m / 784, rem = m % 784;
                size_t ob = (size_t)n * 200704 + rem;
                #pragma unroll
                for (int ch = 0; ch < 32; ++ch) {
                    int c = nh * 128 + wn * 64 + r2 * 32 + ch;
                    out[ob + (size_t)c * 784] = ep[ch * 65 + lane] * scale;
                }
            }
        }
        __syncthreads();
    }
#undef AON
#undef STG
#undef DS_AV0
#undef DS_AV1
#undef DS_BV
#undef MM
#undef LGKM
#undef VM0
#undef BAR
}

// ---------------------------------------------------------------------------
extern "C" void kernel_launch(void* const* d_in, const int* in_sizes, int n_in,
                              void* d_out, int out_size, void* d_ws, size_t ws_size,
                              hipStream_t stream) {
    const float* x  = (const float*)d_in[0];
    const float* wl = (const float*)d_in[1];
    const float* wp = (const float*)d_in[2];
    const float* mu = (const float*)d_in[3];
    float* out = (float*)d_out;
    char* ws = (char*)d_ws;

    int* cntB = (int*)ws;                     // = dropped
    int* cntA = (int*)(ws + 4);
    u16* xt = (u16*)(ws + XT_OFF);
    u16* wt = (u16*)(ws + WT_OFF);
    int* listA = (int*)(ws + LISTA_OFF);
    int* listB = (int*)(ws + LISTB_OFF);

    hipMemsetAsync(ws, 0, 8, stream);

    prep_kernel<<<2692, 256, 0, stream>>>(x, wl, wp, mu, xt, wt,
                                          listA, listB, cntB, cntA);
    conv_kernel<<<456, 256, 0, stream>>>((const char*)xt, (const char*)wt,
                                         listA, listB, cntB, out);
}

// Round 18
// 103.409 us; speedup vs baseline: 1.7893x; 1.1214x over previous
//
#include <hip/hip_runtime.h>
#include <hip/hip_bf16.h>

// ---------------------------------------------------------------------------
// DropBlock fused dual-conv, LIST-COMPACTED implicit GEMM (each position
// computes ONLY its selected branch -> half the FLOPs of dual-conv).
//   prep: mask -> block-chunk (256-contiguous-m) compaction into listA/listB
//         (one atomic per block + 4-wave LDS scan -> lists are m-ordered runs
//         of 256: near-sequential A-gather locality in conv).
//         xt transform now stages through LDS -> coalesced u32 stores.
//   conv: tile = 224 list-positions x 128 channels of ONE branch.
//         Virtual tiles: [0,naT) -> listA, [naT,naT+nbT) -> listB; grid 456
//         (8x57 XCD-bijective), empty tiles exit. Ragged tails clamp to
//         cnt-1 (duplicate rows -> duplicate identical stores, benign).
// Conv core = round-12 proven pipeline: 256 thr (4 waves of 112x64),
//   2-slot LDS dbuf (22528 B/slot, padded 55296 -> exactly 2 blocks/CU),
//   depth-1 VM(0)+BAR per K-tile, split LGKM, setprio, 16x16x32 MFMA.
// ws: [0,4) cntB(dropped) | [4,8) cntA | [65536,+29491200) xt bf16
//     [64][30][30][256] | [29556736,+2359296) wt bf16 [72][4 nq][128][4 ps][8]
//     | [31916032,+200704) listA | [32116736,+200704) listB
// ---------------------------------------------------------------------------

typedef __bf16  bf16x8 __attribute__((ext_vector_type(8)));
typedef float   f32x4  __attribute__((ext_vector_type(4)));
typedef short   short8 __attribute__((ext_vector_type(8)));
typedef unsigned int u32;
typedef unsigned short u16;

#define XT_OFF     65536
#define WT_OFF     29556736
#define LISTA_OFF  31916032
#define LISTB_OFF  32116736
#define SLOT       22528

__device__ __forceinline__ u16 f2bf(float v) {
    u32 u = __float_as_uint(v);
    u32 r = (u + 0x7FFFu + ((u >> 16) & 1u)) >> 16;
    return (u16)r;
}

__device__ __forceinline__ void gll16(const void* g, void* l) {
    __builtin_amdgcn_global_load_lds(
        (const __attribute__((address_space(1))) u32*)g,
        (__attribute__((address_space(3))) u32*)l, 16, 0, 0);
}

// ---------------- fused prep: xt transform + wt swizzle + mask/lists -------
__global__ void prep_kernel(const float* __restrict__ x,
                            const float* __restrict__ wl,
                            const float* __restrict__ wp,
                            const float* __restrict__ mu,
                            u16* __restrict__ xt, u16* __restrict__ wt,
                            int* __restrict__ listA, int* __restrict__ listB,
                            int* __restrict__ cntB, int* __restrict__ cntA) {
    int b = blockIdx.x, tid = threadIdx.x;
    if (b < 1920) {                                   // ---- xt: 64*30 rows
        int n = b / 30, oh = b % 30;
        u16* row = xt + (size_t)(n * 30 + oh) * 30 * 256;
        if (oh == 0 || oh == 29) {                    // halo rows: full zero
            u32* r32 = (u32*)row;
            #pragma unroll
            for (int i = 0; i < 15; ++i) r32[i * 256 + tid] = 0;
            return;
        }
        __shared__ u16 sm[7168];                      // [28 w][256 c]
        int h = oh - 1;
        const float* src = x + ((size_t)(n * 256 + tid) * 28 + h) * 28;
        float f[28];
        #pragma unroll
        for (int q = 0; q < 7; ++q) {
            float4 v = *(const float4*)(src + q * 4);
            f[q * 4 + 0] = v.x; f[q * 4 + 1] = v.y;
            f[q * 4 + 2] = v.z; f[q * 4 + 3] = v.w;
        }
        #pragma unroll
        for (int w = 0; w < 28; ++w)
            sm[w * 256 + tid] = f2bf(f[w]);           // 2-way banks: free
        __syncthreads();
        u32* r32 = (u32*)row;
        if (tid < 128) r32[tid] = 0;                  // halo col ow=0
        else           r32[29 * 128 + (tid - 128)] = 0;   // halo col ow=29
        const u32* s32 = (const u32*)sm;
        u32* dst = r32 + 128;                         // ow=1..28 contiguous
        #pragma unroll
        for (int k = 0; k < 14; ++k)                  // 3584 u32 coalesced
            dst[k * 256 + tid] = s32[k * 256 + tid];
    } else if (b < 2496) {                            // ---- wt blocks (x8 vec)
        // block bb = t*4 + nq: [row 0..127][ps 0..3][jj 0..7]
        // phys slot ps holds logical channels (ps ^ ((row>>1)&3))*8 + jj
        int gid = (b - 1920) * 256 + tid;             // 147456 exact
        int base = gid << 3;                          // 8 elems, jj = 0..7
        int bb = base >> 12;                          // 0..287
        int e = base & 4095;
        int t = bb >> 2, nq = bb & 3;
        int kk = t >> 3;                              // tap 0..8
        int row = e >> 5, ps = (e & 31) >> 3;
        int c0 = (t & 7) * 32 + ((ps ^ ((row >> 1) & 3)) << 3);
        int o = nq * 128 + row;
        const float* wsrc = (o < 256) ? wl : wp;
        const float* wr = wsrc + ((size_t)(o & 255) * 256 + c0) * 9 + kk;
        short8 v;
        #pragma unroll
        for (int j = 0; j < 8; ++j) v[j] = (short)f2bf(wr[j * 9]);
        *(short8*)(wt + base) = v;
    } else {                                          // ---- mask + list build
        __shared__ int lsum[4];
        __shared__ int basB, basA;
        int m = (b - 2496) * 256 + tid;               // 196*256 exact
        int n = m / 784, rem = m % 784;
        int h = rem / 28, w = rem % 28;
        const float g = (float)(0.1 / 49.0);
        const float* un = mu + n * 784;
        int p = 0;
        for (int dy = -3; dy <= 3; ++dy) {
            int hh = h + dy;
            if (hh < 0 || hh >= 28) continue;
            for (int dx = -3; dx <= 3; ++dx) {
                int ww = w + dx;
                if (ww < 0 || ww >= 28) continue;
                p |= (un[hh * 28 + ww] < g) ? 1 : 0;
            }
        }
        unsigned long long ball = __ballot(p);
        int wid = tid >> 6, ln = tid & 63;
        if (ln == 0) lsum[wid] = __popcll(ball);
        __syncthreads();
        if (tid == 0) {
            int tB = lsum[0] + lsum[1] + lsum[2] + lsum[3];
            basB = atomicAdd(cntB, tB);
            basA = atomicAdd(cntA, 256 - tB);
        }
        __syncthreads();
        int offB = 0, offA = 0;
        for (int i = 0; i < wid; ++i) { offB += lsum[i]; offA += 64 - lsum[i]; }
        int rank1 = __popcll(ball & ((1ULL << ln) - 1));
        int rank0 = ln - rank1;
        if (p) listB[basB + offB + rank1] = m;
        else   listA[basA + offA + rank0] = m;
    }
}

// ---------------- list-compacted implicit-GEMM conv + scale ----------------
__global__ __launch_bounds__(256, 2)
void conv_kernel(const char* __restrict__ xt,    // bf16 padded NHWC (bytes)
                 const char* __restrict__ wt,    // bf16 swizzled blocks (bytes)
                 const int* __restrict__ listA,
                 const int* __restrict__ listB,
                 const int* __restrict__ dropped,   // = cntB
                 float* __restrict__ out) {
    __shared__ char smem[55296];                  // 2 slots x 22528 (+pad)
    const int tid = threadIdx.x;
    const int lb = (blockIdx.x & 7) * 57 + (blockIdx.x >> 3);  // 456 = 8*57
    const int vt = lb >> 1;                  // virtual tile 0..227
    const int nh = lb & 1;                   // channel half of the branch
    const int cB = *dropped;
    const int cA = 50176 - cB;
    const int naT = (cA + 223) / 224;
    const int nbT = (cB + 223) / 224;
    if (vt >= naT + nbT) return;             // block-uniform exit
    const int branch = (vt >= naT) ? 1 : 0;
    const int tix = branch ? (vt - naT) : vt;
    const int cnt = branch ? cB : cA;
    const int* lst = branch ? listB : listA;
    const int nq = branch * 2 + nh;          // wt quarter
    const int lane = tid & 63, wave = tid >> 6;
    const int lane15 = lane & 15, grp = lane >> 4;
    const int wm = wave >> 1, wn = wave & 1; // per-wave 112 x 64 output

    // --- A staging source bases (via list gather); swizzle folded in ---
    // op i (i<3): rows i*64 + (tid>>2); op 3 (tid<128): rows 192 + (tid>>2)
    long pbA[4];
    {
        int swz = ((tid & 3) ^ ((tid >> 3) & 3)) << 4;
        #pragma unroll
        for (int i = 0; i < 4; ++i) {
            int r = i * 64 + (tid >> 2);
            int idx = tix * 224 + r;
            if (idx >= cnt) idx = cnt - 1;   // ragged-tail clamp (dup rows)
            int m = lst[idx];
            int n = m / 784, rem = m % 784;
            pbA[i] = (long)(((n * 30 + rem / 28 + 1) * 30 + (rem % 28 + 1)) * 512
                            + swz);
        }
    }

    f32x4 acc[7][4];
    #pragma unroll
    for (int i = 0; i < 7; ++i)
        #pragma unroll
        for (int j = 0; j < 4; ++j)
            acc[i][j] = (f32x4){0.f, 0.f, 0.f, 0.f};

    const int so  = (grp ^ ((lane15 >> 1) & 3)) << 4;        // read swizzle
    const int arb = wm * 7168 + (lane15 << 6) + so;          // A base in slot
    const int brb = 14336 + wn * 4096 + (lane15 << 6) + so;  // B base in slot

#define AON(TC) ((long)((TC) >> 3) / 3 * 15360 + (long)(((TC) >> 3) % 3) * 512 \
                 - 15872 + (long)(((TC) & 7) << 6))
#define STG(TC, SL) { char* sd_ = smem + (SL) * SLOT;                       \
        const long ao_ = AON(TC);                                           \
        gll16(xt + pbA[0] + ao_, sd_ + (tid << 4));                         \
        gll16(xt + pbA[1] + ao_, sd_ + 4096 + (tid << 4));                  \
        gll16(xt + pbA[2] + ao_, sd_ + 8192 + (tid << 4));                  \
        if (tid < 128) gll16(xt + pbA[3] + ao_, sd_ + 12288 + (tid << 4));  \
        const char* wb_ = wt + ((size_t)((TC) * 4 + nq) << 13);             \
        gll16(wb_ + (tid << 4), sd_ + 14336 + (tid << 4));                  \
        gll16(wb_ + 4096 + (tid << 4), sd_ + 18432 + (tid << 4)); }
#define DS_AV0(dst, SL) { const char* sb_ = smem + (SL) * SLOT;             \
        _Pragma("unroll")                                                   \
        for (int fm = 0; fm < 4; ++fm)                                      \
            dst[fm] = *(const bf16x8*)(sb_ + arb + (fm << 10)); }
#define DS_AV1(dst, SL) { const char* sb_ = smem + (SL) * SLOT + 4096;      \
        _Pragma("unroll")                                                   \
        for (int fm = 0; fm < 3; ++fm)                                      \
            dst[fm] = *(const bf16x8*)(sb_ + arb + (fm << 10)); }
#define DS_BV(dst, SL) { const char* sb_ = smem + (SL) * SLOT;              \
        _Pragma("unroll")                                                   \
        for (int fn = 0; fn < 4; ++fn)                                      \
            dst[fn] = *(const bf16x8*)(sb_ + brb + (fn << 10)); }
#define MM(A0_, NF, AV, BV) { __builtin_amdgcn_s_setprio(1);                \
        _Pragma("unroll")                                                   \
        for (int fm = 0; fm < (NF); ++fm)                                   \
            _Pragma("unroll")                                               \
            for (int fn = 0; fn < 4; ++fn)                                  \
                acc[(A0_)+fm][fn] = __builtin_amdgcn_mfma_f32_16x16x32_bf16( \
                    AV[fm], BV[fn], acc[(A0_)+fm][fn], 0, 0, 0);            \
        __builtin_amdgcn_s_setprio(0); }
#define LGKM(N) { asm volatile("s_waitcnt lgkmcnt(" #N ")" ::: "memory");   \
                  __builtin_amdgcn_sched_barrier(0); }
#define VM0     { asm volatile("s_waitcnt vmcnt(0)" ::: "memory");          \
                  __builtin_amdgcn_sched_barrier(0); }
#define BAR     asm volatile("s_barrier" ::: "memory")

    bf16x8 av0[4], av1[3], bv[4];

    // --- prologue: stage tile 0 into slot 0 ---
    STG(0, 0);
    VM0;
    BAR;

    for (int t = 0; t < 72; ++t) {
        const int sc = t & 1, ss = sc ^ 1;
        if (t < 71) STG(t + 1, ss);
        DS_AV0(av0, sc);
        DS_BV(bv, sc);
        DS_AV1(av1, sc);
        LGKM(3);                    // av0+bv ready; av1 still landing
        MM(0, 4, av0, bv);
        LGKM(0);                    // av1 ready
        MM(4, 3, av1, bv);
        VM0;                        // tile t+1 staged & landed
        BAR;
    }

    // --- epilogue: per-wave LDS transpose -> coalesced scaled stores ---
    float scale = 50176.0f / (float)(50176 - cB);
    float* ep = (float*)smem + wave * 2080;      // private [32][65] f32
    __syncthreads();
    #pragma unroll
    for (int rr = 0; rr < 4; ++rr) {
        const int r2 = rr & 1;        // 32-channel half of this wave's 64
        const int mh = rr >> 1;       // m half: 0 -> 64 pos, 1 -> 48 pos
        const int nf = mh ? 3 : 4;
        for (int fm2 = 0; fm2 < nf; ++fm2)
            #pragma unroll
            for (int f2 = 0; f2 < 2; ++f2)
                #pragma unroll
                for (int j = 0; j < 4; ++j)
                    ep[(f2 * 16 + lane15) * 65 + fm2 * 16 + grp * 4 + j] =
                        acc[mh * 4 + fm2][r2 * 2 + f2][j];
        __syncthreads();
        {
            int gidx = tix * 224 + wm * 112 + mh * 64 + lane;
            if ((mh == 0 || lane < 48) && gidx < cnt) {
                int m = lst[gidx];
                int n = m / 784, rem = m % 784;
                size_t ob = (size_t)n * 200704 + rem;
                #pragma unroll
                for (int ch = 0; ch < 32; ++ch) {
                    int c = nh * 128 + wn * 64 + r2 * 32 + ch;
                    out[ob + (size_t)c * 784] = ep[ch * 65 + lane] * scale;
                }
            }
        }
        __syncthreads();
    }
#undef AON
#undef STG
#undef DS_AV0
#undef DS_AV1
#undef DS_BV
#undef MM
#undef LGKM
#undef VM0
#undef BAR
}

// ---------------------------------------------------------------------------
extern "C" void kernel_launch(void* const* d_in, const int* in_sizes, int n_in,
                              void* d_out, int out_size, void* d_ws, size_t ws_size,
                              hipStream_t stream) {
    const float* x  = (const float*)d_in[0];
    const float* wl = (const float*)d_in[1];
    const float* wp = (const float*)d_in[2];
    const float* mu = (const float*)d_in[3];
    float* out = (float*)d_out;
    char* ws = (char*)d_ws;

    int* cntB = (int*)ws;                     // = dropped
    int* cntA = (int*)(ws + 4);
    u16* xt = (u16*)(ws + XT_OFF);
    u16* wt = (u16*)(ws + WT_OFF);
    int* listA = (int*)(ws + LISTA_OFF);
    int* listB = (int*)(ws + LISTB_OFF);

    hipMemsetAsync(ws, 0, 8, stream);

    prep_kernel<<<2692, 256, 0, stream>>>(x, wl, wp, mu, xt, wt,
                                          listA, listB, cntB, cntA);
    conv_kernel<<<456, 256, 0, stream>>>((const char*)xt, (const char*)wt,
                                         listA, listB, cntB, out);
}